// Round 4
// baseline (519.258 us; speedup 1.0000x reference)
//
#include <hip/hip_runtime.h>
#include <hip/hip_bf16.h>
#include <stdint.h>

typedef unsigned short ushort_t;
typedef __attribute__((ext_vector_type(8))) short bf16x8;
typedef __attribute__((ext_vector_type(4))) float f32x4;
typedef __attribute__((ext_vector_type(4))) unsigned short ushort4_t;

__device__ __forceinline__ unsigned short f2b(float f) {
    __hip_bfloat16 h = __float2bfloat16(f);
    return __builtin_bit_cast(unsigned short, h);
}

__device__ __forceinline__ float leaky(float v) {
    return v >= 0.0f ? v : 0.2f * v;
}

__device__ __forceinline__ void gld16(const void* g, void* l) {
    __builtin_amdgcn_global_load_lds(
        (const __attribute__((address_space(1))) void*)g,
        (__attribute__((address_space(3))) void*)l, 16, 0, 0);
}

// ---------------------------------------------------------------------------
// Transpose + f32->bf16 convert: in [K][N] f32 -> out [N][K] bf16 bits
// 64x64 tiles, LDS staged, padded to kill bank conflicts.
// ---------------------------------------------------------------------------
__global__ __launch_bounds__(256)
void transpose_cvt(const float* __restrict__ in, ushort_t* __restrict__ out,
                   int K, int N) {
    __shared__ float t[64][65];
    const int k0 = blockIdx.x * 64, n0 = blockIdx.y * 64;
    const int tx = threadIdx.x & 15, ty = threadIdx.x >> 4;
#pragma unroll
    for (int i = 0; i < 4; ++i) {
        const float4 v = *(const float4*)&in[(size_t)(k0 + ty + i * 16) * N + n0 + tx * 4];
        t[ty + i * 16][tx * 4 + 0] = v.x;
        t[ty + i * 16][tx * 4 + 1] = v.y;
        t[ty + i * 16][tx * 4 + 2] = v.z;
        t[ty + i * 16][tx * 4 + 3] = v.w;
    }
    __syncthreads();
#pragma unroll
    for (int i = 0; i < 4; ++i) {
        const int n = ty + i * 16;
        ushort4_t o;
        o[0] = f2b(t[tx * 4 + 0][n]);
        o[1] = f2b(t[tx * 4 + 1][n]);
        o[2] = f2b(t[tx * 4 + 2][n]);
        o[3] = f2b(t[tx * 4 + 3][n]);
        *(ushort4_t*)&out[(size_t)(n0 + n) * K + k0 + tx * 4] = o;
    }
}

// ---------------------------------------------------------------------------
// h1[b][:] = leaky(W1[x[b]][:] + b1) as bf16. One block per row.
// ---------------------------------------------------------------------------
__global__ __launch_bounds__(256)
void gather_leaky(const int* __restrict__ x, const float* __restrict__ W1,
                  const float* __restrict__ b1, ushort_t* __restrict__ h1) {
    const int row = blockIdx.x;
    const int t = threadIdx.x;
    const int idx = x[row];
    const float4 w = *(const float4*)&W1[(size_t)idx * 1024 + t * 4];
    const float4 b = *(const float4*)&b1[t * 4];
    ushort4_t o;
    o[0] = f2b(leaky(w.x + b.x));
    o[1] = f2b(leaky(w.y + b.y));
    o[2] = f2b(leaky(w.z + b.z));
    o[3] = f2b(leaky(w.w + b.w));
    *(ushort4_t*)&h1[(size_t)row * 1024 + t * 4] = o;
}

// ---------------------------------------------------------------------------
// bf16 GEMM: C[M][N] = A[M][K] * Bt[N][K]^T + bias
// 4 waves in 2x2, BK=64, global_load_lds width16 with XOR-preswizzled source,
// mfma_f32_16x16x32_bf16.  A-frag: lane holds A[l&15][(l>>4)*8+j];
// B-frag: lane holds B[(l>>4)*8+j][l&15] = Bt[l&15][(l>>4)*8+j];
// D: row=(l>>4)*4+r, col=l&15  (guide m89-verified).
// ---------------------------------------------------------------------------
template <int BM, int BN>
__global__ __launch_bounds__(256, 2)
void gemm_bf16(const ushort_t* __restrict__ A, const ushort_t* __restrict__ Bt,
               const float* __restrict__ bias, float* __restrict__ C,
               int M, int N, int K) {
    constexpr int BK = 64;                    // 128 bytes per LDS row
    constexpr int FM = BM / 32, FN = BN / 32; // 16x16 frags per wave
    __shared__ ushort_t sA[BM * BK];
    __shared__ ushort_t sB[BN * BK];
    const int tid = threadIdx.x;
    const int lane = tid & 63;
    const int wv = tid >> 6;
    const int wr = wv >> 1, wc = wv & 1;
    const int lr = lane & 15, lq = lane >> 4;
    const int brow = blockIdx.x * BM;
    const int bcol = blockIdx.y * BN;

    f32x4 acc[FM][FN] = {};

    for (int k0 = 0; k0 < K; k0 += BK) {
        // stage A tile: rows of 128B; LDS(row,chunk j) = global(row, j ^ (row&7))
#pragma unroll
        for (int i = 0; i < BM / 32; ++i) {
            const int c = i * 256 + tid;
            const int row = c >> 3;
            const int src = ((c & 7) ^ (row & 7)) * 8; // elem offset in row
            gld16(&A[(size_t)(brow + row) * K + k0 + src], &sA[c * 8]);
        }
#pragma unroll
        for (int i = 0; i < BN / 32; ++i) {
            const int c = i * 256 + tid;
            const int row = c >> 3;
            const int src = ((c & 7) ^ (row & 7)) * 8;
            gld16(&Bt[(size_t)(bcol + row) * K + k0 + src], &sB[c * 8]);
        }
        __syncthreads();

#pragma unroll
        for (int kk = 0; kk < 2; ++kk) {
            bf16x8 af[FM], bfr[FN];
#pragma unroll
            for (int m = 0; m < FM; ++m) {
                const int r = wr * (BM / 2) + m * 16 + lr;
                const int boff = (kk * 64 + lq * 16) ^ ((r & 7) << 4);
                af[m] = *(const bf16x8*)((const char*)sA + r * 128 + boff);
            }
#pragma unroll
            for (int n = 0; n < FN; ++n) {
                const int r = wc * (BN / 2) + n * 16 + lr;
                const int boff = (kk * 64 + lq * 16) ^ ((r & 7) << 4);
                bfr[n] = *(const bf16x8*)((const char*)sB + r * 128 + boff);
            }
#pragma unroll
            for (int m = 0; m < FM; ++m)
#pragma unroll
                for (int n = 0; n < FN; ++n)
                    acc[m][n] = __builtin_amdgcn_mfma_f32_16x16x32_bf16(
                        af[m], bfr[n], acc[m][n], 0, 0, 0);
        }
        __syncthreads();
    }

#pragma unroll
    for (int m = 0; m < FM; ++m) {
#pragma unroll
        for (int n = 0; n < FN; ++n) {
            const int col = bcol + wc * (BN / 2) + n * 16 + lr;
            const float bv = bias[col];
#pragma unroll
            for (int r = 0; r < 4; ++r) {
                const int row = brow + wr * (BM / 2) + m * 16 + lq * 4 + r;
                C[(size_t)row * N + col] = acc[m][n][r] + bv;
            }
        }
    }
}

// ---------------------------------------------------------------------------
// Row LayerNorm + leaky + bf16 cast. One block (256 thr) per row of 1024.
// ---------------------------------------------------------------------------
__global__ __launch_bounds__(256)
void ln_leaky(const float* __restrict__ pre, const float* __restrict__ g,
              const float* __restrict__ beta, ushort_t* __restrict__ h2) {
    const int row = blockIdx.x;
    const int t = threadIdx.x;
    const float4 v = *(const float4*)&pre[(size_t)row * 1024 + t * 4];
    float s = v.x + v.y + v.z + v.w;
    float s2 = v.x * v.x + v.y * v.y + v.z * v.z + v.w * v.w;
#pragma unroll
    for (int off = 32; off > 0; off >>= 1) {
        s += __shfl_down(s, off, 64);
        s2 += __shfl_down(s2, off, 64);
    }
    __shared__ float red[8];
    if ((t & 63) == 0) {
        red[(t >> 6) * 2 + 0] = s;
        red[(t >> 6) * 2 + 1] = s2;
    }
    __syncthreads();
    s = red[0] + red[2] + red[4] + red[6];
    s2 = red[1] + red[3] + red[5] + red[7];
    const float mu = s * (1.0f / 1024.0f);
    const float var = s2 * (1.0f / 1024.0f) - mu * mu;
    const float rs = rsqrtf(var + 1e-5f);
    const float4 gv = *(const float4*)&g[t * 4];
    const float4 bv = *(const float4*)&beta[t * 4];
    ushort4_t o;
    o[0] = f2b(leaky((v.x - mu) * rs * gv.x + bv.x));
    o[1] = f2b(leaky((v.y - mu) * rs * gv.y + bv.y));
    o[2] = f2b(leaky((v.z - mu) * rs * gv.z + bv.z));
    o[3] = f2b(leaky((v.w - mu) * rs * gv.w + bv.w));
    *(ushort4_t*)&h2[(size_t)row * 1024 + t * 4] = o;
}

// ---------------------------------------------------------------------------
extern "C" void kernel_launch(void* const* d_in, const int* in_sizes, int n_in,
                              void* d_out, int out_size, void* d_ws, size_t ws_size,
                              hipStream_t stream) {
    const int* x = (const int*)d_in[0];
    const float* W1 = (const float*)d_in[1];
    const float* b1 = (const float*)d_in[2];
    const float* W2 = (const float*)d_in[3];
    const float* b2 = (const float*)d_in[4];
    const float* g2 = (const float*)d_in[5];
    const float* bt2 = (const float*)d_in[6];
    const float* W3 = (const float*)d_in[7];
    const float* b3 = (const float*)d_in[8];
    float* out = (float*)d_out;

    // Workspace layout (h2 aliases h1: h1 is dead after GEMM1):
    //   h1/h2 : 8192*1024*2 = 16 MiB   @ 0
    //   W2t   : 1024*1024*2 =  2 MiB   @ 16 MiB
    //   W3t   :  256*1024*2 = 512 KiB  @ 18 MiB
    //   pre   : 8192*1024*4 = 32 MiB   @ 18.5 MiB
    // total ~50.5 MiB
    char* ws = (char*)d_ws;
    ushort_t* h1 = (ushort_t*)(ws);
    ushort_t* W2t = (ushort_t*)(ws + 16777216);
    ushort_t* W3t = (ushort_t*)(ws + 18874368);
    float* pre = (float*)(ws + 19398656);
    ushort_t* h2 = h1;

    transpose_cvt<<<dim3(16, 16), 256, 0, stream>>>(W2, W2t, 1024, 1024);
    transpose_cvt<<<dim3(16, 4), 256, 0, stream>>>(W3, W3t, 1024, 256);
    gather_leaky<<<8192, 256, 0, stream>>>(x, W1, b1, h1);
    gemm_bf16<128, 128><<<dim3(64, 8), 256, 0, stream>>>(h1, W2t, b2, pre, 8192, 1024, 1024);
    ln_leaky<<<8192, 256, 0, stream>>>(pre, g2, bt2, h2);
    gemm_bf16<128, 64><<<dim3(64, 4), 256, 0, stream>>>(h2, W3t, b3, out, 8192, 256, 1024);
}